// Round 5
// baseline (309.123 us; speedup 1.0000x reference)
//
#include <hip/hip_runtime.h>
#include <hip/hip_bf16.h>
#include <cstdint>
#include <cstddef>

// ---------------------------------------------------------------------------
// GraphHINGE, round 4: MFMA logits + MFMA Hbar, 8-node tiles, 3 barriers.
//  prep:  build_BmatT (bf16 [m][384][128]), conv_WcT (bf16 [m][128][384]),
//         conv_pw1T (bf16 [128][128])
//  fused_all (grid 10240 = 5 metapaths x 2048 tiles, 256 thr, dyn LDS 39.4KB):
//   ph1: gather + cross-corr -> Hs rows (bf16) + Ht transposed [e][p] + H0
//   ph2: S = H0 @ BmatT (MFMA, M=8 nodes, N=384, K=128)
//   ph3 (per wave, 2 nodes): logits = S.H^T (MFMA) -> in-wave softmax ->
//        alpha (bf16, zero-padded K=32) -> Hbar = alpha.H (MFMA via Ht)
//   ph4: Z = Hbar @ WcT / 3 (MFMA) -> scatter into Zall (bf16)
//  fused_tail (512 blocks x 512 thr): unchanged from round 3.
// ---------------------------------------------------------------------------

typedef __hip_bfloat16 bf16;
typedef __attribute__((ext_vector_type(8))) short  bfrag;   // 8 bf16 (4 VGPR)
typedef __attribute__((ext_vector_type(4))) float  ffrag;   // 4 f32 acc

#define NNODES 16384

__device__ __forceinline__ float bflo(uint32_t u) { return __uint_as_float(u << 16); }
__device__ __forceinline__ float bfhi(uint32_t u) { return __uint_as_float(u & 0xffff0000u); }
__device__ __forceinline__ uint16_t f2bfu(float x) {
  bf16 h = __float2bfloat16(x);
  return *(uint16_t*)&h;
}
__device__ __forceinline__ uint32_t pk2(float lo, float hi) {
  return (uint32_t)f2bfu(lo) | ((uint32_t)f2bfu(hi) << 16);
}

// ---------------- prep: BmatT[m][h*128+e][ep] = Ws[m,h,e,:].Wt[m,h,ep,:] ---
__global__ __launch_bounds__(256) void build_BmatT(
    const float* __restrict__ Ws, const float* __restrict__ Wt,
    bf16* __restrict__ BmT)
{
  int mh = blockIdx.x >> 4;   // m*3+h
  int g  = blockIdx.x & 15;
  int m = mh / 3, h = mh % 3;
  const float* ws = Ws + (size_t)mh * 16384;
  const float* wt = Wt + (size_t)mh * 16384;
  int tid = threadIdx.x;
  int e = tid & 127, half = tid >> 7;
  __shared__ float wtl[2][128];
  for (int ep0 = g * 8; ep0 < g * 8 + 8; ep0 += 2) {
    int ep = ep0 + half;
    wtl[half][e] = wt[ep * 128 + e];
    __syncthreads();
    float acc = 0.f;
    #pragma unroll 4
    for (int o = 0; o < 128; ++o) acc += ws[e * 128 + o] * wtl[half][o];
    BmT[((size_t)(m * 384 + h * 128 + e)) * 128 + ep] = __float2bfloat16(acc);
    __syncthreads();
  }
}

// ---------------- prep: WcT[m][o][he] = Wc[m][he][o] -----------------------
__global__ __launch_bounds__(256) void conv_WcT(
    const float* __restrict__ Wc, bf16* __restrict__ WcT)
{
  int idx = blockIdx.x * 256 + threadIdx.x;   // < 5*128*384
  int he = idx % 384, mo = idx / 384;
  int m = mo >> 7, o = mo & 127;
  WcT[idx] = __float2bfloat16(Wc[((size_t)m * 384 + he) * 128 + o]);
}

// ---------------- prep: pw1T[o][k] = pw1[k][o] -----------------------------
__global__ __launch_bounds__(256) void conv_pw1T(
    const float* __restrict__ pw1, bf16* __restrict__ pw1T)
{
  int idx = blockIdx.x * 256 + threadIdx.x;   // < 16384
  int o = idx >> 7, k = idx & 127;
  pw1T[idx] = __float2bfloat16(pw1[(size_t)k * 128 + o]);
}

// ---------------- fused per-metapath body (8 nodes, 256 threads) -----------
template <int P>
__device__ __forceinline__ void metapath_body(
    char* smem,
    const float* __restrict__ Tu0, const float* __restrict__ Tu1,
    const float* __restrict__ Tu2, const float* __restrict__ Tu3,
    const float* __restrict__ Tt0, const float* __restrict__ Tt1,
    const float* __restrict__ Tt2, const float* __restrict__ Tt3,
    const int* __restrict__ idxU, const int* __restrict__ idxT,
    const bf16* __restrict__ BmT,    // [384][128] (this metapath)
    const bf16* __restrict__ WcT,    // [128][384]
    bf16* __restrict__ Zall, int m, int tile)
{
  constexpr int PP = 2 * P - 1;
  constexpr int NS = PP * 136;       // per-node Hs stride (bf16)
  bf16* Hs = (bf16*)smem;                         // [8][PP][136]
  bf16* Ht = Hs + 8 * NS;                         // [8][128][8]  (p-slots, 0-pad)
  bf16* Ss = Ht + 8 * 1024;                       // [8][392]     (S, then Hbar)
  bf16* Al = Ss + 8 * 392;                        // [8][3][32]   (alpha, 0-pad)

  int tid = threadIdx.x;
  int lane = tid & 63, wid = tid >> 6;
  int l15 = lane & 15, l4 = lane >> 4;
  int n0 = tile * 8;

  // ---- phase 0/1: zero alpha pads; gather (hoisted) + corr -> Hs, Ht ----
  {
    for (int i = tid; i < 8 * 96 / 2; i += 256) ((uint32_t*)Al)[i] = 0;
    const float* TU[4] = {Tu0, Tu1, Tu2, Tu3};
    const float* TT[4] = {Tt0, Tt1, Tt2, Tt3};
    int e = tid & 127;
    float su[4][P], st[4][P];
    #pragma unroll
    for (int g = 0; g < 4; ++g) {
      int n = n0 + g * 2 + (tid >> 7);
      #pragma unroll
      for (int p = 0; p < P; ++p) {
        su[g][p] = TU[p][(size_t)idxU[n * P + p] * 128 + e];
        st[g][p] = TT[p][(size_t)idxT[n * P + p] * 128 + e];
      }
    }
    #pragma unroll
    for (int g = 0; g < 4; ++g) {
      int ln = g * 2 + (tid >> 7);
      float acc[PP];
      #pragma unroll
      for (int k = 0; k < PP; ++k) {
        float a = 0.f;
        #pragma unroll
        for (int i = 0; i < P; ++i) {
          int j = k + i - (P - 1);
          if (j >= 0 && j < P) a += su[g][j] * st[g][i];
        }
        acc[k] = a;
        Hs[ln * NS + k * 136 + e] = __float2bfloat16(a);
      }
      // transposed copy: Ht[ln][e][0..7] = H[0..7][e] (p>=PP -> 0)
      int4 w;
      w.x = pk2(acc[0], acc[1]);
      w.y = pk2(acc[2], (PP > 3) ? acc[3] : 0.f);
      if (PP > 3) {
        w.z = pk2(acc[4], acc[5]);
        w.w = pk2(acc[6], 0.f);
      } else {
        w.z = 0; w.w = 0;
      }
      *(int4*)&Ht[(ln * 128 + e) * 8] = w;
    }
  }
  __syncthreads();

  // ---- phase 2: S = H0 @ BmatT : M=8(16), N=384, K=128 (4 waves x 6 frags)
  {
    bfrag a[4];
    int nrow = (l15 < 7) ? l15 : 7;
    #pragma unroll
    for (int kk = 0; kk < 4; ++kk)
      a[kk] = *(const bfrag*)&Hs[nrow * NS + kk * 32 + 8 * l4];   // H0 row
    #pragma unroll
    for (int f = 0; f < 6; ++f) {
      int col = wid * 96 + f * 16 + l15;
      ffrag acc = {0.f, 0.f, 0.f, 0.f};
      #pragma unroll
      for (int kk = 0; kk < 4; ++kk) {
        bfrag b = *(const bfrag*)&BmT[(size_t)col * 128 + kk * 32 + 8 * l4];
        acc = __builtin_amdgcn_mfma_f32_16x16x32_bf16(a[kk], b, acc, 0, 0, 0);
      }
      #pragma unroll
      for (int r = 0; r < 4; ++r) {
        int node = 4 * l4 + r;
        if (node < 8) Ss[node * 392 + col] = __float2bfloat16(acc[r]);
      }
    }
  }
  __syncthreads();

  // ---- phase 3 (per wave, nodes 2*wid, 2*wid+1):
  //      logits = S.H^T (MFMA) -> in-wave softmax -> alpha -> Hbar (MFMA) ----
  {
    int hrow = (l15 < 2) ? l15 : 2;
    int prow = (l15 < PP - 1) ? l15 : (PP - 1);
    #pragma unroll
    for (int nn = 0; nn < 2; ++nn) {
      int node = wid * 2 + nn;
      const bf16* SsN = Ss + node * 392;
      const bf16* HsN = Hs + node * NS;
      // logits[h][p] = sum_e S[h][e] H[p][e]
      ffrag lacc = {0.f, 0.f, 0.f, 0.f};
      #pragma unroll
      for (int kk = 0; kk < 4; ++kk) {
        bfrag a = *(const bfrag*)&SsN[hrow * 128 + kk * 32 + 8 * l4];
        bfrag b = *(const bfrag*)&HsN[prow * 136 + kk * 32 + 8 * l4];
        lacc = __builtin_amdgcn_mfma_f32_16x16x32_bf16(a, b, lacc, 0, 0, 0);
      }
      bool val = (l4 == 0) && (l15 < PP);
      float l0 = val ? lacc[0] * 5.0f : -1e30f;   // /T1
      float l1 = val ? lacc[1] * 5.0f : -1e30f;
      float l2 = val ? lacc[2] * 5.0f : -1e30f;
      float m0 = l0, m1 = l1, m2 = l2;
      #pragma unroll
      for (int d = 1; d < 8; d <<= 1) {
        m0 = fmaxf(m0, __shfl_xor(m0, d));
        m1 = fmaxf(m1, __shfl_xor(m1, d));
        m2 = fmaxf(m2, __shfl_xor(m2, d));
      }
      float e0 = val ? __expf(l0 - m0) : 0.f;
      float e1 = val ? __expf(l1 - m1) : 0.f;
      float e2 = val ? __expf(l2 - m2) : 0.f;
      float s0 = e0, s1 = e1, s2 = e2;
      #pragma unroll
      for (int d = 1; d < 8; d <<= 1) {
        s0 += __shfl_xor(s0, d);
        s1 += __shfl_xor(s1, d);
        s2 += __shfl_xor(s2, d);
      }
      if (val) {
        Al[node * 96 +      l15] = __float2bfloat16(e0 / s0);
        Al[node * 96 + 32 + l15] = __float2bfloat16(e1 / s1);
        Al[node * 96 + 64 + l15] = __float2bfloat16(e2 / s2);
      }
      // Hbar[h][e] = sum_p alpha[h][p] H[p][e]  (K=32, alpha zero-padded)
      bfrag aa = *(const bfrag*)&Al[node * 96 + hrow * 32 + 8 * l4];
      #pragma unroll
      for (int f = 0; f < 8; ++f) {
        bfrag bb = *(const bfrag*)&Ht[(node * 128 + f * 16 + l15) * 8];
        ffrag hb = {0.f, 0.f, 0.f, 0.f};
        hb = __builtin_amdgcn_mfma_f32_16x16x32_bf16(aa, bb, hb, 0, 0, 0);
        if (l4 == 0) {
          #pragma unroll
          for (int r = 0; r < 3; ++r)
            Ss[node * 392 + r * 128 + f * 16 + l15] = __float2bfloat16(hb[r]);
        }
      }
    }
  }
  __syncthreads();

  // ---- phase 4: Z = Hbar @ WcT / 3 : M=8(16), N=128, K=384 (4 w x 2 frags)
  {
    bfrag a[12];
    int nrow = (l15 < 7) ? l15 : 7;
    #pragma unroll
    for (int kk = 0; kk < 12; ++kk)
      a[kk] = *(const bfrag*)&Ss[nrow * 392 + kk * 32 + 8 * l4];
    #pragma unroll
    for (int f = 0; f < 2; ++f) {
      int col = wid * 32 + f * 16 + l15;
      ffrag acc = {0.f, 0.f, 0.f, 0.f};
      #pragma unroll
      for (int kk = 0; kk < 12; ++kk) {
        bfrag b = *(const bfrag*)&WcT[(size_t)col * 384 + kk * 32 + 8 * l4];
        acc = __builtin_amdgcn_mfma_f32_16x16x32_bf16(a[kk], b, acc, 0, 0, 0);
      }
      #pragma unroll
      for (int r = 0; r < 4; ++r) {
        int node = 4 * l4 + r;
        if (node < 8) {
          int gn = n0 + node;
          int crow = (((gn >> 5) * 5 + m) << 5) + (gn & 31);
          Zall[(size_t)crow * 128 + col] =
              __float2bfloat16(acc[r] * (1.0f / 3.0f));
        }
      }
    }
  }
}

// ---------------- all 5 metapaths in one launch ----------------------------
// grid = 10240: bid>>11 = m, bid&2047 = tile
__global__ __launch_bounds__(256, 4) void fused_all(
    const float* __restrict__ emb_user, const float* __restrict__ emb_item,
    const float* __restrict__ emb_a1, const float* __restrict__ emb_a2,
    const float* __restrict__ emb_a3,
    const int* __restrict__ UI,    const int* __restrict__ IU,
    const int* __restrict__ UIUI,  const int* __restrict__ IUIU,
    const int* __restrict__ UIAI1, const int* __restrict__ IAIU1,
    const int* __restrict__ UIAI2, const int* __restrict__ IAIU2,
    const int* __restrict__ UIAI3, const int* __restrict__ IAIU3,
    const bf16* __restrict__ BmT, const bf16* __restrict__ WcT,
    bf16* __restrict__ Zall)
{
  extern __shared__ char smem[];
  int bid = blockIdx.x;
  int m = bid >> 11, tile = bid & 2047;
  if (m == 0) {
    metapath_body<2>(smem, emb_user, emb_item, nullptr, nullptr,
                     emb_item, emb_user, nullptr, nullptr,
                     UI, IU, BmT, WcT, Zall, 0, tile);
  } else {
    const float* u2 = (m == 1) ? emb_user : (m == 2) ? emb_a1
                    : (m == 3) ? emb_a2 : emb_a3;
    const int* iu_ = (m == 1) ? UIUI : (m == 2) ? UIAI1
                   : (m == 3) ? UIAI2 : UIAI3;
    const int* it_ = (m == 1) ? IUIU : (m == 2) ? IAIU1
                   : (m == 3) ? IAIU2 : IAIU3;
    metapath_body<4>(smem, emb_user, emb_item, u2, emb_item,
                     emb_item, u2, emb_item, emb_user,
                     iu_, it_,
                     BmT + (size_t)m * 49152, WcT + (size_t)m * 49152,
                     Zall, m, tile);
  }
}

// ---------------- fused tail: tanh-GEMM + w + beta + pout + final MLP ------
// block = 1 batch element b, 512 threads (8 waves); grid = 512
__global__ __launch_bounds__(512) void fused_tail(
    const bf16* __restrict__ Zall,    // [512*160][128], row b*160+j
    const bf16* __restrict__ pw1T,    // [128][128] (o-major)
    const float* __restrict__ pb1, const float* __restrict__ pw2,
    const int* __restrict__ UI, const int* __restrict__ IU,
    const float* __restrict__ emb_user, const float* __restrict__ emb_item,
    const float* __restrict__ fw1, const float* __restrict__ fb1,
    const float* __restrict__ fw2, const float* __restrict__ fb2,
    float* __restrict__ out)
{
  __shared__ bf16 Zs[160 * 136];
  __shared__ float wrow[160];
  __shared__ float ph[4][128];
  __shared__ float xs[384];
  __shared__ float sred[16];
  __shared__ float yred[2];

  int b = blockIdx.x, tid = threadIdx.x;
  int lane = tid & 63, wid = tid >> 6;
  int l15 = lane & 15, l4 = lane >> 4;

  // ---- stage z-block (160x128 bf16) -> LDS, raw 16B copies, hoisted ----
  {
    const float4* src = (const float4*)(Zall + (size_t)b * 160 * 128);
    float4 v[5];
    #pragma unroll
    for (int i = 0; i < 5; ++i) v[i] = src[i * 512 + tid];
    #pragma unroll
    for (int i = 0; i < 5; ++i) {
      int idx = i * 512 + tid;            // 0..2559
      int row = idx >> 4, c8 = idx & 15;
      *(float4*)&Zs[row * 136 + c8 * 8] = v[i];
    }
  }
  __syncthreads();

  // ---- w[row] = (tanh(z@pw1+pb1).pw2)*5 : M=160,N=128,K=128 ----
  for (int rf = wid; rf < 10; rf += 8) {
    bfrag a[4];
    #pragma unroll
    for (int kk = 0; kk < 4; ++kk)
      a[kk] = *(const bfrag*)&Zs[(rf * 16 + l15) * 136 + kk * 32 + 8 * l4];
    float part[4] = {0.f, 0.f, 0.f, 0.f};
    #pragma unroll
    for (int f = 0; f < 8; ++f) {
      int col = f * 16 + l15;
      ffrag acc = {0.f, 0.f, 0.f, 0.f};
      #pragma unroll
      for (int kk = 0; kk < 4; ++kk) {
        bfrag bv = *(const bfrag*)&pw1T[(size_t)col * 128 + kk * 32 + 8 * l4];
        acc = __builtin_amdgcn_mfma_f32_16x16x32_bf16(a[kk], bv, acc, 0, 0, 0);
      }
      float bias = pb1[col], w2 = pw2[col];
      #pragma unroll
      for (int r = 0; r < 4; ++r) part[r] += tanhf(acc[r] + bias) * w2;
    }
    #pragma unroll
    for (int d = 1; d < 16; d <<= 1) {
      #pragma unroll
      for (int r = 0; r < 4; ++r) part[r] += __shfl_xor(part[r], d);
    }
    if (l15 == 0) {
      #pragma unroll
      for (int r = 0; r < 4; ++r)
        wrow[rf * 16 + 4 * l4 + r] = part[r] * 5.0f;   // /T2
    }
  }
  __syncthreads();

  // ---- softmax over 160 paths (wave-parallel) ----
  {
    float v = (tid < 160) ? wrow[tid] : -1e30f;
    #pragma unroll
    for (int off = 32; off; off >>= 1) v = fmaxf(v, __shfl_xor(v, off));
    if (lane == 0) sred[wid] = v;
    __syncthreads();
    if (tid < 64) {
      float mval = (lane < 8) ? sred[lane] : -1e30f;
      #pragma unroll
      for (int off = 4; off; off >>= 1) mval = fmaxf(mval, __shfl_xor(mval, off));
      if (lane == 0) sred[8] = mval;
    }
    __syncthreads();
    float mx = sred[8];
    float ev = (tid < 160) ? __expf(wrow[tid] - mx) : 0.f;
    float s = ev;
    #pragma unroll
    for (int off = 32; off; off >>= 1) s += __shfl_xor(s, off);
    if (lane == 0) sred[wid] = s;
    __syncthreads();
    if (tid < 64) {
      float sval = (lane < 8) ? sred[lane] : 0.f;
      #pragma unroll
      for (int off = 4; off; off >>= 1) sval += __shfl_xor(sval, off);
      if (lane == 0) sred[9] = sval;
    }
    __syncthreads();
    if (tid < 160) wrow[tid] = ev / sred[9];
  }
  __syncthreads();

  // ---- pout[e] = sum_j beta[j]*z[j][e]  (4-way split over j) ----
  {
    int e = tid & 127, q = tid >> 7;
    float acc = 0.f;
    #pragma unroll 4
    for (int j = q * 40; j < q * 40 + 40; ++j)
      acc += wrow[j] * __bfloat162float(Zs[j * 136 + e]);
    ph[q][e] = acc;
  }
  __syncthreads();

  // ---- build x = [src_emb, tgt_emb, pout] ----
  {
    int su = UI[b * 64];   // UI[b][0][0]
    int ti = IU[b * 64];   // IU[b][0][0]
    if (tid < 128) {
      xs[256 + tid] = ph[0][tid] + ph[1][tid] + ph[2][tid] + ph[3][tid];
    } else if (tid < 256) {
      xs[tid - 128] = emb_user[(size_t)su * 128 + (tid - 128)];
    } else if (tid < 384) {
      xs[tid - 128] = emb_item[(size_t)ti * 128 + (tid - 256)];
    }
  }
  __syncthreads();

  // ---- final: y = relu(x@fw1+fb1); out = sigmoid(y.fw2+fb2) ----
  {
    int o = tid & 127, q = tid >> 7;
    float acc = 0.f;
    #pragma unroll 4
    for (int i = q * 96; i < q * 96 + 96; ++i)
      acc += xs[i] * fw1[(size_t)i * 128 + o];
    __syncthreads();          // ph free now
    ph[q][o] = acc;
  }
  __syncthreads();
  if (tid < 128) {
    float y = fmaxf(ph[0][tid] + ph[1][tid] + ph[2][tid] + ph[3][tid] + fb1[tid],
                    0.0f) * fw2[tid];
    #pragma unroll
    for (int off = 32; off; off >>= 1) y += __shfl_down(y, off);
    if ((tid & 63) == 0) yred[tid >> 6] = y;
  }
  __syncthreads();
  if (tid == 0) {
    float s = yred[0] + yred[1] + fb2[0];
    out[b] = 1.0f / (1.0f + expf(-s));
  }
}

// ---------------------------------------------------------------------------
extern "C" void kernel_launch(void* const* d_in, const int* in_sizes, int n_in,
                              void* d_out, int out_size, void* d_ws, size_t ws_size,
                              hipStream_t stream)
{
  const int* UI    = (const int*)d_in[0];
  const int* IU    = (const int*)d_in[1];
  const int* UIUI  = (const int*)d_in[2];
  const int* IUIU  = (const int*)d_in[3];
  const int* UIAI1 = (const int*)d_in[4];
  const int* IAIU1 = (const int*)d_in[5];
  const int* UIAI2 = (const int*)d_in[6];
  const int* IAIU2 = (const int*)d_in[7];
  const int* UIAI3 = (const int*)d_in[8];
  const int* IAIU3 = (const int*)d_in[9];
  const float* emb_user = (const float*)d_in[10];
  const float* emb_item = (const float*)d_in[11];
  const float* emb_a1   = (const float*)d_in[12];
  const float* emb_a2   = (const float*)d_in[13];
  const float* emb_a3   = (const float*)d_in[14];
  const float* Wt  = (const float*)d_in[15];
  const float* Ws  = (const float*)d_in[16];
  const float* Wc  = (const float*)d_in[17];
  const float* pw1 = (const float*)d_in[18];
  const float* pb1 = (const float*)d_in[19];
  const float* pw2 = (const float*)d_in[20];
  const float* fw1 = (const float*)d_in[21];
  const float* fb1 = (const float*)d_in[22];
  const float* fw2 = (const float*)d_in[23];
  const float* fb2 = (const float*)d_in[24];
  float* out = (float*)d_out;

  // ---- workspace carve (bytes) ----
  char* wsb = (char*)d_ws;
  bf16*  BmT  = (bf16*)wsb;                         // 491,520 B
  bf16*  WcT  = (bf16*)(wsb + 491520);              // 491,520 B
  bf16*  pw1T = (bf16*)(wsb + 983040);              //  32,768 B
  bf16*  Zall = (bf16*)(wsb + 1015808);             // 20,971,520 B

  build_BmatT<<<240, 256, 0, stream>>>(Ws, Wt, BmT);
  conv_WcT<<<960, 256, 0, stream>>>(Wc, WcT);
  conv_pw1T<<<64, 256, 0, stream>>>(pw1, pw1T);

  // dyn LDS (PP=7): Hs 8*952*2 + Ht 8*1024*2 + Ss 8*392*2 + Al 8*96*2
  //              = 15232 + 16384 + 6272 + 1536 = 39424 B
  fused_all<<<10240, 256, 39424, stream>>>(
      emb_user, emb_item, emb_a1, emb_a2, emb_a3,
      UI, IU, UIUI, IUIU, UIAI1, IAIU1, UIAI2, IAIU2, UIAI3, IAIU3,
      BmT, WcT, Zall);

  fused_tail<<<512, 512, 0, stream>>>(Zall, pw1T, pb1, pw2,
                                      UI, IU, emb_user, emb_item,
                                      fw1, fb1, fw2, fb2, out);
}

// Round 6
// 241.564 us; speedup vs baseline: 1.2797x; 1.2797x over previous
//
#include <hip/hip_runtime.h>
#include <hip/hip_bf16.h>
#include <cstdint>
#include <cstddef>

// ---------------------------------------------------------------------------
// GraphHINGE, round 5: round-3 structure (512 thr / 16-node tiles, validated
// at 216 us) + latency fixes in the middle phase:
//  - logits: 4 independent accumulators, uint2 LDS loads, h-rotated iteration
//    (kills the 64-step serial FMA chain + 3-way bank conflict on S rows)
//  - softmax: in-wave via rotation shfls (no LDS, no barriers)
//  - Hbar: alpha via __shfl from owning lanes (no LDS round-trip)
//  Phases: gather | S (MFMA) | logits+softmax+Hbar | Z (MFMA)  = 3 barriers.
// ---------------------------------------------------------------------------

typedef __hip_bfloat16 bf16;
typedef __attribute__((ext_vector_type(8))) short  bfrag;   // 8 bf16 (4 VGPR)
typedef __attribute__((ext_vector_type(4))) float  ffrag;   // 4 f32 acc

#define NNODES 16384

__device__ __forceinline__ float bflo(uint32_t u) { return __uint_as_float(u << 16); }
__device__ __forceinline__ float bfhi(uint32_t u) { return __uint_as_float(u & 0xffff0000u); }
__device__ __forceinline__ uint16_t f2bfu(float x) {
  bf16 h = __float2bfloat16(x);
  return *(uint16_t*)&h;
}
__device__ __forceinline__ uint32_t pk2(float lo, float hi) {
  return (uint32_t)f2bfu(lo) | ((uint32_t)f2bfu(hi) << 16);
}

// ---------------- prep: BmatT[m][h*128+e][ep] = Ws[m,h,e,:].Wt[m,h,ep,:] ---
__global__ __launch_bounds__(256) void build_BmatT(
    const float* __restrict__ Ws, const float* __restrict__ Wt,
    bf16* __restrict__ BmT)
{
  int mh = blockIdx.x >> 4;   // m*3+h
  int g  = blockIdx.x & 15;
  int m = mh / 3, h = mh % 3;
  const float* ws = Ws + (size_t)mh * 16384;
  const float* wt = Wt + (size_t)mh * 16384;
  int tid = threadIdx.x;
  int e = tid & 127, half = tid >> 7;
  __shared__ float wtl[2][128];
  for (int ep0 = g * 8; ep0 < g * 8 + 8; ep0 += 2) {
    int ep = ep0 + half;
    wtl[half][e] = wt[ep * 128 + e];
    __syncthreads();
    float acc = 0.f;
    #pragma unroll 4
    for (int o = 0; o < 128; ++o) acc += ws[e * 128 + o] * wtl[half][o];
    BmT[((size_t)(m * 384 + h * 128 + e)) * 128 + ep] = __float2bfloat16(acc);
    __syncthreads();
  }
}

// ---------------- prep: WcT[m][o][he] = Wc[m][he][o] -----------------------
__global__ __launch_bounds__(256) void conv_WcT(
    const float* __restrict__ Wc, bf16* __restrict__ WcT)
{
  int idx = blockIdx.x * 256 + threadIdx.x;   // < 5*128*384
  int he = idx % 384, mo = idx / 384;
  int m = mo >> 7, o = mo & 127;
  WcT[idx] = __float2bfloat16(Wc[((size_t)m * 384 + he) * 128 + o]);
}

// ---------------- prep: pw1T[o][k] = pw1[k][o] -----------------------------
__global__ __launch_bounds__(256) void conv_pw1T(
    const float* __restrict__ pw1, bf16* __restrict__ pw1T)
{
  int idx = blockIdx.x * 256 + threadIdx.x;   // < 16384
  int o = idx >> 7, k = idx & 127;
  pw1T[idx] = __float2bfloat16(pw1[(size_t)k * 128 + o]);
}

// ---------------- fused per-metapath body (16 nodes, 512 threads) ----------
template <int P>
__device__ __forceinline__ void metapath_body(
    char* smem,
    const float* __restrict__ Tu0, const float* __restrict__ Tu1,
    const float* __restrict__ Tu2, const float* __restrict__ Tu3,
    const float* __restrict__ Tt0, const float* __restrict__ Tt1,
    const float* __restrict__ Tt2, const float* __restrict__ Tt3,
    const int* __restrict__ idxU, const int* __restrict__ idxT,
    const bf16* __restrict__ BmT,    // [384][128] (this metapath)
    const bf16* __restrict__ WcT,    // [128][384]
    bf16* __restrict__ Zall, int m, int tile)
{
  constexpr int PP = 2 * P - 1;
  constexpr int NS = PP * 136;       // node stride in Hs (bf16)
  constexpr int NPAIR = 3 * PP;
  bf16* Hs = (bf16*)smem;                          // [16][PP][136]
  bf16* Ss = Hs + 16 * NS;                         // [16][392] (S, then Hbar)

  int tid = threadIdx.x;
  int lane = tid & 63, wid = tid >> 6;
  int l15 = lane & 15, l4 = lane >> 4;
  int n0 = tile * 16;

  // ---- phase 1: gather (all loads hoisted) + cross-correlate -> Hs ----
  {
    const float* TU[4] = {Tu0, Tu1, Tu2, Tu3};
    const float* TT[4] = {Tt0, Tt1, Tt2, Tt3};
    int e = tid & 127;
    float su[4][P], st[4][P];
    #pragma unroll
    for (int g = 0; g < 4; ++g) {
      int n = n0 + g * 4 + (tid >> 7);
      #pragma unroll
      for (int p = 0; p < P; ++p) {
        su[g][p] = TU[p][(size_t)idxU[n * P + p] * 128 + e];
        st[g][p] = TT[p][(size_t)idxT[n * P + p] * 128 + e];
      }
    }
    #pragma unroll
    for (int g = 0; g < 4; ++g) {
      int ln = g * 4 + (tid >> 7);
      bf16* Hn = &Hs[ln * NS + e];
      #pragma unroll
      for (int k = 0; k < PP; ++k) {
        float acc = 0.f;
        #pragma unroll
        for (int i = 0; i < P; ++i) {
          int j = k + i - (P - 1);
          if (j >= 0 && j < P) acc += su[g][j] * st[g][i];
        }
        Hn[k * 136] = __float2bfloat16(acc);
      }
    }
  }
  __syncthreads();

  // ---- phase 2: S = H0 @ BmatT : M=16, N=384, K=128 (8 waves x 3 frags) ---
  {
    bfrag a[4];
    #pragma unroll
    for (int kk = 0; kk < 4; ++kk)
      a[kk] = *(const bfrag*)&Hs[l15 * NS + kk * 32 + 8 * l4];   // H0 row
    #pragma unroll
    for (int f = 0; f < 3; ++f) {
      int col = wid * 48 + f * 16 + l15;
      ffrag acc = {0.f, 0.f, 0.f, 0.f};
      #pragma unroll
      for (int kk = 0; kk < 4; ++kk) {
        bfrag b = *(const bfrag*)&BmT[(size_t)col * 128 + kk * 32 + 8 * l4];
        acc = __builtin_amdgcn_mfma_f32_16x16x32_bf16(a[kk], b, acc, 0, 0, 0);
      }
      #pragma unroll
      for (int r = 0; r < 4; ++r) {
        int node = 4 * l4 + r;
        Ss[node * 392 + col] = __float2bfloat16(acc[r]);
      }
    }
  }
  __syncthreads();

  // ---- phase 3: logits -> in-wave softmax -> Hbar (no barriers inside) ----
  {
    int node = tid >> 5, q = tid & 31;
    int h = q / PP, p = q - h * PP;        // valid for q < NPAIR
    float alpha_mine = 0.f;
    float lg = -1e30f;
    if (q < NPAIR) {
      // logits[h][p] = sum_e H[p][e]*S[h][e]; 4 indep acc chains, b64 loads,
      // iteration rotated by h*10 uint2-slots (bank-disjoint h-lanes)
      const uint2* hrow = (const uint2*)&Hs[node * NS + p * 136];
      const uint2* srow = (const uint2*)&Ss[node * 392 + h * 128];
      float acc[4] = {0.f, 0.f, 0.f, 0.f};
      int rot = h * 10;
      #pragma unroll
      for (int ii = 0; ii < 32; ++ii) {
        int iu = (ii + rot) & 31;
        uint2 hv = hrow[iu], sv = srow[iu];
        float t = bflo(hv.x) * bflo(sv.x) + bfhi(hv.x) * bfhi(sv.x)
                + bflo(hv.y) * bflo(sv.y) + bfhi(hv.y) * bfhi(sv.y);
        acc[ii & 3] += t;
      }
      lg = (acc[0] + acc[1] + acc[2] + acc[3]) * 5.0f;   // /T1
    }
    // in-wave softmax over the PP-lane group [base, base+PP)
    int base = (lane & 32) + h * PP;
    float mx = lg;
    #pragma unroll
    for (int d = 1; d < PP; ++d) {
      int pd = p + d; if (pd >= PP) pd -= PP;
      mx = fmaxf(mx, __shfl(lg, base + pd, 64));
    }
    float ex = __expf(lg - mx);
    float sm = ex;
    #pragma unroll
    for (int d = 1; d < PP; ++d) {
      int pd = p + d; if (pd >= PP) pd -= PP;
      sm += __shfl(ex, base + pd, 64);
    }
    alpha_mine = ex / sm;                  // garbage for q >= NPAIR (unused)

    // Hbar[node][h2*128+e2..e2+1] = sum_p alpha[h2][p]*H[p][e2..e2+1]
    int hb = lane & 32;
    #pragma unroll
    for (int c = 0; c < 6; ++c) {
      int o2 = q * 6 + c;                  // 0..191
      int h2 = o2 >> 6, e2 = (o2 & 63) * 2;
      float a0 = 0.f, a1 = 0.f;
      #pragma unroll
      for (int pp = 0; pp < PP; ++pp) {
        float al = __shfl(alpha_mine, hb + h2 * PP + pp, 64);
        uint32_t hv = *(const uint32_t*)&Hs[node * NS + pp * 136 + e2];
        a0 += al * bflo(hv);
        a1 += al * bfhi(hv);
      }
      *(uint32_t*)&Ss[node * 392 + h2 * 128 + e2] = pk2(a0, a1);
    }
  }
  __syncthreads();

  // ---- phase 4: Z = Hbar @ WcT / 3 : M=16, N=128, K=384 (8 w x 1 frag) ----
  {
    bfrag a[12];
    #pragma unroll
    for (int kk = 0; kk < 12; ++kk)
      a[kk] = *(const bfrag*)&Ss[l15 * 392 + kk * 32 + 8 * l4];
    int col = wid * 16 + l15;
    ffrag acc = {0.f, 0.f, 0.f, 0.f};
    #pragma unroll
    for (int kk = 0; kk < 12; ++kk) {
      bfrag b = *(const bfrag*)&WcT[(size_t)col * 384 + kk * 32 + 8 * l4];
      acc = __builtin_amdgcn_mfma_f32_16x16x32_bf16(a[kk], b, acc, 0, 0, 0);
    }
    #pragma unroll
    for (int r = 0; r < 4; ++r) {
      int gn = n0 + 4 * l4 + r;
      int crow = (((gn >> 5) * 5 + m) << 5) + (gn & 31);
      Zall[(size_t)crow * 128 + col] = __float2bfloat16(acc[r] * (1.0f / 3.0f));
    }
  }
}

// ---------------- all 5 metapaths in one launch ----------------------------
// grid = 5120: bid>>10 = m, bid&1023 = tile
__global__ __launch_bounds__(512) void fused_all(
    const float* __restrict__ emb_user, const float* __restrict__ emb_item,
    const float* __restrict__ emb_a1, const float* __restrict__ emb_a2,
    const float* __restrict__ emb_a3,
    const int* __restrict__ UI,    const int* __restrict__ IU,
    const int* __restrict__ UIUI,  const int* __restrict__ IUIU,
    const int* __restrict__ UIAI1, const int* __restrict__ IAIU1,
    const int* __restrict__ UIAI2, const int* __restrict__ IAIU2,
    const int* __restrict__ UIAI3, const int* __restrict__ IAIU3,
    const bf16* __restrict__ BmT, const bf16* __restrict__ WcT,
    bf16* __restrict__ Zall)
{
  extern __shared__ char smem[];
  int bid = blockIdx.x;
  int m = bid >> 10, tile = bid & 1023;
  if (m == 0) {
    metapath_body<2>(smem, emb_user, emb_item, nullptr, nullptr,
                     emb_item, emb_user, nullptr, nullptr,
                     UI, IU, BmT, WcT, Zall, 0, tile);
  } else {
    const float* u2 = (m == 1) ? emb_user : (m == 2) ? emb_a1
                    : (m == 3) ? emb_a2 : emb_a3;
    const int* iu_ = (m == 1) ? UIUI : (m == 2) ? UIAI1
                   : (m == 3) ? UIAI2 : UIAI3;
    const int* it_ = (m == 1) ? IUIU : (m == 2) ? IAIU1
                   : (m == 3) ? IAIU2 : IAIU3;
    metapath_body<4>(smem, emb_user, emb_item, u2, emb_item,
                     emb_item, u2, emb_item, emb_user,
                     iu_, it_,
                     BmT + (size_t)m * 49152, WcT + (size_t)m * 49152,
                     Zall, m, tile);
  }
}

// ---------------- fused tail: tanh-GEMM + w + beta + pout + final MLP ------
// block = 1 batch element b, 512 threads (8 waves); grid = 512
__global__ __launch_bounds__(512) void fused_tail(
    const bf16* __restrict__ Zall,    // [512*160][128], row b*160+j
    const bf16* __restrict__ pw1T,    // [128][128] (o-major)
    const float* __restrict__ pb1, const float* __restrict__ pw2,
    const int* __restrict__ UI, const int* __restrict__ IU,
    const float* __restrict__ emb_user, const float* __restrict__ emb_item,
    const float* __restrict__ fw1, const float* __restrict__ fb1,
    const float* __restrict__ fw2, const float* __restrict__ fb2,
    float* __restrict__ out)
{
  __shared__ bf16 Zs[160 * 136];
  __shared__ float wrow[160];
  __shared__ float ph[4][128];
  __shared__ float xs[384];
  __shared__ float sred[16];
  __shared__ float yred[2];

  int b = blockIdx.x, tid = threadIdx.x;
  int lane = tid & 63, wid = tid >> 6;
  int l15 = lane & 15, l4 = lane >> 4;

  // ---- stage z-block (160x128 bf16) -> LDS, raw 16B copies, hoisted ----
  {
    const float4* src = (const float4*)(Zall + (size_t)b * 160 * 128);
    float4 v[5];
    #pragma unroll
    for (int i = 0; i < 5; ++i) v[i] = src[i * 512 + tid];
    #pragma unroll
    for (int i = 0; i < 5; ++i) {
      int idx = i * 512 + tid;            // 0..2559
      int row = idx >> 4, c8 = idx & 15;
      *(float4*)&Zs[row * 136 + c8 * 8] = v[i];
    }
  }
  __syncthreads();

  // ---- w[row] = (tanh(z@pw1+pb1).pw2)*5 : M=160,N=128,K=128 ----
  for (int rf = wid; rf < 10; rf += 8) {
    bfrag a[4];
    #pragma unroll
    for (int kk = 0; kk < 4; ++kk)
      a[kk] = *(const bfrag*)&Zs[(rf * 16 + l15) * 136 + kk * 32 + 8 * l4];
    float part[4] = {0.f, 0.f, 0.f, 0.f};
    #pragma unroll
    for (int f = 0; f < 8; ++f) {
      int col = f * 16 + l15;
      ffrag acc = {0.f, 0.f, 0.f, 0.f};
      #pragma unroll
      for (int kk = 0; kk < 4; ++kk) {
        bfrag bv = *(const bfrag*)&pw1T[(size_t)col * 128 + kk * 32 + 8 * l4];
        acc = __builtin_amdgcn_mfma_f32_16x16x32_bf16(a[kk], bv, acc, 0, 0, 0);
      }
      float bias = pb1[col], w2 = pw2[col];
      #pragma unroll
      for (int r = 0; r < 4; ++r) part[r] += tanhf(acc[r] + bias) * w2;
    }
    #pragma unroll
    for (int d = 1; d < 16; d <<= 1) {
      #pragma unroll
      for (int r = 0; r < 4; ++r) part[r] += __shfl_xor(part[r], d);
    }
    if (l15 == 0) {
      #pragma unroll
      for (int r = 0; r < 4; ++r)
        wrow[rf * 16 + 4 * l4 + r] = part[r] * 5.0f;   // /T2
    }
  }
  __syncthreads();

  // ---- softmax over 160 paths (wave-parallel) ----
  {
    float v = (tid < 160) ? wrow[tid] : -1e30f;
    #pragma unroll
    for (int off = 32; off; off >>= 1) v = fmaxf(v, __shfl_xor(v, off));
    if (lane == 0) sred[wid] = v;
    __syncthreads();
    if (tid < 64) {
      float mval = (lane < 8) ? sred[lane] : -1e30f;
      #pragma unroll
      for (int off = 4; off; off >>= 1) mval = fmaxf(mval, __shfl_xor(mval, off));
      if (lane == 0) sred[8] = mval;
    }
    __syncthreads();
    float mx = sred[8];
    float ev = (tid < 160) ? __expf(wrow[tid] - mx) : 0.f;
    float s = ev;
    #pragma unroll
    for (int off = 32; off; off >>= 1) s += __shfl_xor(s, off);
    if (lane == 0) sred[wid] = s;
    __syncthreads();
    if (tid < 64) {
      float sval = (lane < 8) ? sred[lane] : 0.f;
      #pragma unroll
      for (int off = 4; off; off >>= 1) sval += __shfl_xor(sval, off);
      if (lane == 0) sred[9] = sval;
    }
    __syncthreads();
    if (tid < 160) wrow[tid] = ev / sred[9];
  }
  __syncthreads();

  // ---- pout[e] = sum_j beta[j]*z[j][e]  (4-way split over j) ----
  {
    int e = tid & 127, q = tid >> 7;
    float acc = 0.f;
    #pragma unroll 4
    for (int j = q * 40; j < q * 40 + 40; ++j)
      acc += wrow[j] * __bfloat162float(Zs[j * 136 + e]);
    ph[q][e] = acc;
  }
  __syncthreads();

  // ---- build x = [src_emb, tgt_emb, pout] ----
  {
    int su = UI[b * 64];   // UI[b][0][0]
    int ti = IU[b * 64];   // IU[b][0][0]
    if (tid < 128) {
      xs[256 + tid] = ph[0][tid] + ph[1][tid] + ph[2][tid] + ph[3][tid];
    } else if (tid < 256) {
      xs[tid - 128] = emb_user[(size_t)su * 128 + (tid - 128)];
    } else if (tid < 384) {
      xs[tid - 128] = emb_item[(size_t)ti * 128 + (tid - 256)];
    }
  }
  __syncthreads();

  // ---- final: y = relu(x@fw1+fb1); out = sigmoid(y.fw2+fb2) ----
  {
    int o = tid & 127, q = tid >> 7;
    float acc = 0.f;
    #pragma unroll 4
    for (int i = q * 96; i < q * 96 + 96; ++i)
      acc += xs[i] * fw1[(size_t)i * 128 + o];
    __syncthreads();          // ph free now
    ph[q][o] = acc;
  }
  __syncthreads();
  if (tid < 128) {
    float y = fmaxf(ph[0][tid] + ph[1][tid] + ph[2][tid] + ph[3][tid] + fb1[tid],
                    0.0f) * fw2[tid];
    #pragma unroll
    for (int off = 32; off; off >>= 1) y += __shfl_down(y, off);
    if ((tid & 63) == 0) yred[tid >> 6] = y;
  }
  __syncthreads();
  if (tid == 0) {
    float s = yred[0] + yred[1] + fb2[0];
    out[b] = 1.0f / (1.0f + expf(-s));
  }
}

// ---------------------------------------------------------------------------
extern "C" void kernel_launch(void* const* d_in, const int* in_sizes, int n_in,
                              void* d_out, int out_size, void* d_ws, size_t ws_size,
                              hipStream_t stream)
{
  const int* UI    = (const int*)d_in[0];
  const int* IU    = (const int*)d_in[1];
  const int* UIUI  = (const int*)d_in[2];
  const int* IUIU  = (const int*)d_in[3];
  const int* UIAI1 = (const int*)d_in[4];
  const int* IAIU1 = (const int*)d_in[5];
  const int* UIAI2 = (const int*)d_in[6];
  const int* IAIU2 = (const int*)d_in[7];
  const int* UIAI3 = (const int*)d_in[8];
  const int* IAIU3 = (const int*)d_in[9];
  const float* emb_user = (const float*)d_in[10];
  const float* emb_item = (const float*)d_in[11];
  const float* emb_a1   = (const float*)d_in[12];
  const float* emb_a2   = (const float*)d_in[13];
  const float* emb_a3   = (const float*)d_in[14];
  const float* Wt  = (const float*)d_in[15];
  const float* Ws  = (const float*)d_in[16];
  const float* Wc  = (const float*)d_in[17];
  const float* pw1 = (const float*)d_in[18];
  const float* pb1 = (const float*)d_in[19];
  const float* pw2 = (const float*)d_in[20];
  const float* fw1 = (const float*)d_in[21];
  const float* fb1 = (const float*)d_in[22];
  const float* fw2 = (const float*)d_in[23];
  const float* fb2 = (const float*)d_in[24];
  float* out = (float*)d_out;

  // ---- workspace carve (bytes) ----
  char* wsb = (char*)d_ws;
  bf16*  BmT  = (bf16*)wsb;                         // 491,520 B
  bf16*  WcT  = (bf16*)(wsb + 491520);              // 491,520 B
  bf16*  pw1T = (bf16*)(wsb + 983040);              //  32,768 B
  bf16*  Zall = (bf16*)(wsb + 1015808);             // 20,971,520 B

  build_BmatT<<<240, 256, 0, stream>>>(Ws, Wt, BmT);
  conv_WcT<<<960, 256, 0, stream>>>(Wc, WcT);
  conv_pw1T<<<64, 256, 0, stream>>>(pw1, pw1T);

  // dyn LDS (PP=7): Hs 16*952*2 + Ss 16*392*2 = 30464 + 12544 = 43008 B
  fused_all<<<5120, 512, 43008, stream>>>(
      emb_user, emb_item, emb_a1, emb_a2, emb_a3,
      UI, IU, UIUI, IUIU, UIAI1, IAIU1, UIAI2, IAIU2, UIAI3, IAIU3,
      BmT, WcT, Zall);

  fused_tail<<<512, 512, 0, stream>>>(Zall, pw1T, pb1, pw2,
                                      UI, IU, emb_user, emb_item,
                                      fw1, fb1, fw2, fb2, out);
}

// Round 7
// 201.773 us; speedup vs baseline: 1.5320x; 1.1972x over previous
//
#include <hip/hip_runtime.h>
#include <hip/hip_bf16.h>
#include <cstdint>
#include <cstddef>

// ---------------------------------------------------------------------------
// GraphHINGE, round 6: round-3 skeleton (512 thr / 16-node tiles / 3 barriers)
// with MFMA-based phase 3:
//  - logits: 2 nodes per wave packed into one 16x16 MFMA chain (K=128, 4 MFMA)
//    A rows {0-2}=S[n0,h], {8-10}=S[n1,h]; B cols {0-6}=H[n0,p], {8-14}=H[n1,p]
//  - softmax: 8-lane butterfly shfl_xor (aligned groups, 18 wave-ops)
//  - alpha: tiny LDS buffer (bf16 [node][3][8]), read back as b128
//  - Hbar: static-indexed VALU, H row loaded once per pp, reused for 3 heads
//  All phase-3 traffic stays within the owning wave -> no extra barriers.
//  Prep kernels merged into one launch.
// ---------------------------------------------------------------------------

typedef __hip_bfloat16 bf16;
typedef __attribute__((ext_vector_type(8))) short  bfrag;   // 8 bf16 (4 VGPR)
typedef __attribute__((ext_vector_type(4))) float  ffrag;   // 4 f32 acc

#define NNODES 16384

__device__ __forceinline__ float bflo(uint32_t u) { return __uint_as_float(u << 16); }
__device__ __forceinline__ float bfhi(uint32_t u) { return __uint_as_float(u & 0xffff0000u); }
__device__ __forceinline__ float bfs(short s) {
  return __uint_as_float(((uint32_t)(unsigned short)s) << 16);
}
__device__ __forceinline__ uint16_t f2bfu(float x) {
  bf16 h = __float2bfloat16(x);
  return *(uint16_t*)&h;
}
__device__ __forceinline__ uint32_t pk2(float lo, float hi) {
  return (uint32_t)f2bfu(lo) | ((uint32_t)f2bfu(hi) << 16);
}

// ---------------- merged prep: BmatT + WcT + pw1T --------------------------
// grid 1264: [0,240) BmatT, [240,1200) WcT, [1200,1264) pw1T
__global__ __launch_bounds__(256) void prep_all(
    const float* __restrict__ Ws, const float* __restrict__ Wt,
    const float* __restrict__ Wc, const float* __restrict__ pw1,
    bf16* __restrict__ BmT, bf16* __restrict__ WcT, bf16* __restrict__ pw1T)
{
  int bid = blockIdx.x;
  int tid = threadIdx.x;
  if (bid < 240) {
    // BmatT[m][h*128+e][ep] = Ws[m,h,e,:].Wt[m,h,ep,:]
    int mh = bid >> 4;   // m*3+h
    int g  = bid & 15;
    int m = mh / 3, h = mh % 3;
    const float* ws = Ws + (size_t)mh * 16384;
    const float* wt = Wt + (size_t)mh * 16384;
    int e = tid & 127, half = tid >> 7;
    __shared__ float wtl[2][128];
    for (int ep0 = g * 8; ep0 < g * 8 + 8; ep0 += 2) {
      int ep = ep0 + half;
      wtl[half][e] = wt[ep * 128 + e];
      __syncthreads();
      float acc = 0.f;
      #pragma unroll 4
      for (int o = 0; o < 128; ++o) acc += ws[e * 128 + o] * wtl[half][o];
      BmT[((size_t)(m * 384 + h * 128 + e)) * 128 + ep] = __float2bfloat16(acc);
      __syncthreads();
    }
  } else if (bid < 1200) {
    // WcT[m][o][he] = Wc[m][he][o]
    int idx = (bid - 240) * 256 + tid;   // < 5*128*384
    int he = idx % 384, mo = idx / 384;
    int m = mo >> 7, o = mo & 127;
    WcT[idx] = __float2bfloat16(Wc[((size_t)m * 384 + he) * 128 + o]);
  } else {
    // pw1T[o][k] = pw1[k][o]
    int idx = (bid - 1200) * 256 + tid;  // < 16384
    int o = idx >> 7, k = idx & 127;
    pw1T[idx] = __float2bfloat16(pw1[(size_t)k * 128 + o]);
  }
}

// ---------------- fused per-metapath body (16 nodes, 512 threads) ----------
template <int P>
__device__ __forceinline__ void metapath_body(
    char* smem,
    const float* __restrict__ Tu0, const float* __restrict__ Tu1,
    const float* __restrict__ Tu2, const float* __restrict__ Tu3,
    const float* __restrict__ Tt0, const float* __restrict__ Tt1,
    const float* __restrict__ Tt2, const float* __restrict__ Tt3,
    const int* __restrict__ idxU, const int* __restrict__ idxT,
    const bf16* __restrict__ BmT,    // [384][128] (this metapath)
    const bf16* __restrict__ WcT,    // [128][384]
    bf16* __restrict__ Zall, int m, int tile)
{
  constexpr int PP = 2 * P - 1;
  constexpr int NS = PP * 136;       // node stride in Hs (bf16)
  bf16* Hs = (bf16*)smem;                          // [16][PP][136]
  bf16* Ss = Hs + 16 * NS;                         // [16][392] (S, then Hbar)
  bf16* Al = Ss + 16 * 392;                        // [16][3][8] alpha

  int tid = threadIdx.x;
  int lane = tid & 63, wid = tid >> 6;
  int l15 = lane & 15, l4 = lane >> 4;
  int n0 = tile * 16;

  // ---- phase 1: gather (all loads hoisted) + cross-correlate -> Hs ----
  {
    const float* TU[4] = {Tu0, Tu1, Tu2, Tu3};
    const float* TT[4] = {Tt0, Tt1, Tt2, Tt3};
    int e = tid & 127;
    float su[4][P], st[4][P];
    #pragma unroll
    for (int g = 0; g < 4; ++g) {
      int n = n0 + g * 4 + (tid >> 7);
      #pragma unroll
      for (int p = 0; p < P; ++p) {
        su[g][p] = TU[p][(size_t)idxU[n * P + p] * 128 + e];
        st[g][p] = TT[p][(size_t)idxT[n * P + p] * 128 + e];
      }
    }
    #pragma unroll
    for (int g = 0; g < 4; ++g) {
      int ln = g * 4 + (tid >> 7);
      bf16* Hn = &Hs[ln * NS + e];
      #pragma unroll
      for (int k = 0; k < PP; ++k) {
        float acc = 0.f;
        #pragma unroll
        for (int i = 0; i < P; ++i) {
          int j = k + i - (P - 1);
          if (j >= 0 && j < P) acc += su[g][j] * st[g][i];
        }
        Hn[k * 136] = __float2bfloat16(acc);
      }
    }
  }
  __syncthreads();

  // ---- phase 2: S = H0 @ BmatT : M=16, N=384, K=128 (8 waves x 3 frags) ---
  {
    bfrag a[4];
    #pragma unroll
    for (int kk = 0; kk < 4; ++kk)
      a[kk] = *(const bfrag*)&Hs[l15 * NS + kk * 32 + 8 * l4];   // H0 row
    #pragma unroll
    for (int f = 0; f < 3; ++f) {
      int col = wid * 48 + f * 16 + l15;
      ffrag acc = {0.f, 0.f, 0.f, 0.f};
      #pragma unroll
      for (int kk = 0; kk < 4; ++kk) {
        bfrag b = *(const bfrag*)&BmT[(size_t)col * 128 + kk * 32 + 8 * l4];
        acc = __builtin_amdgcn_mfma_f32_16x16x32_bf16(a[kk], b, acc, 0, 0, 0);
      }
      #pragma unroll
      for (int r = 0; r < 4; ++r) {
        int node = 4 * l4 + r;
        Ss[node * 392 + col] = __float2bfloat16(acc[r]);
      }
    }
  }
  __syncthreads();

  // ---- phase 3: logits (MFMA, 2 nodes/wave) -> butterfly softmax ->
  //      alpha(LDS) -> Hbar (static VALU). All within-wave, no barriers. ----
  {
    int nd0 = wid * 2, nd1 = nd0 + 1;
    bool hi = (l15 >= 8);
    int nodeA = hi ? nd1 : nd0;
    int r15 = hi ? (l15 - 8) : l15;               // 0..7
    int ah = (r15 < 3) ? r15 : 2;                 // junk-row clamp
    int bp = (r15 < PP) ? r15 : (PP - 1);         // junk-col clamp
    ffrag lacc = {0.f, 0.f, 0.f, 0.f};
    #pragma unroll
    for (int kk = 0; kk < 4; ++kk) {
      bfrag av = *(const bfrag*)&Ss[nodeA * 392 + ah * 128 + kk * 32 + 8 * l4];
      bfrag bv = *(const bfrag*)&Hs[nodeA * NS + bp * 136 + kk * 32 + 8 * l4];
      lacc = __builtin_amdgcn_mfma_f32_16x16x32_bf16(av, bv, lacc, 0, 0, 0);
    }
    // valid: n0 -> lanes 0..PP-1 (l4==0); n1 -> lanes 40..40+PP-1 (l4==2)
    bool val = ((l4 == 0) && !hi && (l15 < PP)) ||
               ((l4 == 2) &&  hi && (r15 < PP));
    float lg0 = val ? lacc[0] * 5.0f : -1e30f;    // /T1
    float lg1 = val ? lacc[1] * 5.0f : -1e30f;
    float lg2 = val ? lacc[2] * 5.0f : -1e30f;
    float m0 = lg0, m1 = lg1, m2 = lg2;
    #pragma unroll
    for (int d = 1; d < 8; d <<= 1) {
      m0 = fmaxf(m0, __shfl_xor(m0, d));
      m1 = fmaxf(m1, __shfl_xor(m1, d));
      m2 = fmaxf(m2, __shfl_xor(m2, d));
    }
    float e0 = val ? __expf(lg0 - m0) : 0.f;
    float e1 = val ? __expf(lg1 - m1) : 0.f;
    float e2 = val ? __expf(lg2 - m2) : 0.f;
    float s0 = e0, s1 = e1, s2 = e2;
    #pragma unroll
    for (int d = 1; d < 8; d <<= 1) {
      s0 += __shfl_xor(s0, d);
      s1 += __shfl_xor(s1, d);
      s2 += __shfl_xor(s2, d);
    }
    if (val) {
      bf16* Aln = Al + nodeA * 24;
      Aln[r15]      = __float2bfloat16(e0 / s0);
      Aln[8 + r15]  = __float2bfloat16(e1 / s1);
      Aln[16 + r15] = __float2bfloat16(e2 / s2);
    }

    // Hbar[node][h*128+e] = sum_p alpha[h][p] * H[p][e]
    int node = tid >> 5, q = tid & 31;
    bfrag al0 = *(const bfrag*)&Al[node * 24];
    bfrag al1 = *(const bfrag*)&Al[node * 24 + 8];
    bfrag al2 = *(const bfrag*)&Al[node * 24 + 16];
    #pragma unroll
    for (int j = 0; j < 2; ++j) {
      int e2i = 4 * q + 2 * j;
      float a00 = 0.f, a01 = 0.f, a10 = 0.f, a11 = 0.f, a20 = 0.f, a21 = 0.f;
      #pragma unroll
      for (int pp = 0; pp < PP; ++pp) {
        uint32_t hv = *(const uint32_t*)&Hs[node * NS + pp * 136 + e2i];
        float lo = bflo(hv), hh = bfhi(hv);
        float f0 = bfs(al0[pp]);
        float f1 = bfs(al1[pp]);
        float f2 = bfs(al2[pp]);
        a00 += f0 * lo; a01 += f0 * hh;
        a10 += f1 * lo; a11 += f1 * hh;
        a20 += f2 * lo; a21 += f2 * hh;
      }
      *(uint32_t*)&Ss[node * 392 +       e2i] = pk2(a00, a01);
      *(uint32_t*)&Ss[node * 392 + 128 + e2i] = pk2(a10, a11);
      *(uint32_t*)&Ss[node * 392 + 256 + e2i] = pk2(a20, a21);
    }
  }
  __syncthreads();

  // ---- phase 4: Z = Hbar @ WcT / 3 : M=16, N=128, K=384 (8 w x 1 frag) ----
  {
    bfrag a[12];
    #pragma unroll
    for (int kk = 0; kk < 12; ++kk)
      a[kk] = *(const bfrag*)&Ss[l15 * 392 + kk * 32 + 8 * l4];
    int col = wid * 16 + l15;
    ffrag acc = {0.f, 0.f, 0.f, 0.f};
    #pragma unroll
    for (int kk = 0; kk < 12; ++kk) {
      bfrag b = *(const bfrag*)&WcT[(size_t)col * 384 + kk * 32 + 8 * l4];
      acc = __builtin_amdgcn_mfma_f32_16x16x32_bf16(a[kk], b, acc, 0, 0, 0);
    }
    #pragma unroll
    for (int r = 0; r < 4; ++r) {
      int gn = n0 + 4 * l4 + r;
      int crow = (((gn >> 5) * 5 + m) << 5) + (gn & 31);
      Zall[(size_t)crow * 128 + col] = __float2bfloat16(acc[r] * (1.0f / 3.0f));
    }
  }
}

// ---------------- all 5 metapaths in one launch ----------------------------
// grid = 5120: bid>>10 = m, bid&1023 = tile
__global__ __launch_bounds__(512) void fused_all(
    const float* __restrict__ emb_user, const float* __restrict__ emb_item,
    const float* __restrict__ emb_a1, const float* __restrict__ emb_a2,
    const float* __restrict__ emb_a3,
    const int* __restrict__ UI,    const int* __restrict__ IU,
    const int* __restrict__ UIUI,  const int* __restrict__ IUIU,
    const int* __restrict__ UIAI1, const int* __restrict__ IAIU1,
    const int* __restrict__ UIAI2, const int* __restrict__ IAIU2,
    const int* __restrict__ UIAI3, const int* __restrict__ IAIU3,
    const bf16* __restrict__ BmT, const bf16* __restrict__ WcT,
    bf16* __restrict__ Zall)
{
  extern __shared__ char smem[];
  int bid = blockIdx.x;
  int m = bid >> 10, tile = bid & 1023;
  if (m == 0) {
    metapath_body<2>(smem, emb_user, emb_item, nullptr, nullptr,
                     emb_item, emb_user, nullptr, nullptr,
                     UI, IU, BmT, WcT, Zall, 0, tile);
  } else {
    const float* u2 = (m == 1) ? emb_user : (m == 2) ? emb_a1
                    : (m == 3) ? emb_a2 : emb_a3;
    const int* iu_ = (m == 1) ? UIUI : (m == 2) ? UIAI1
                   : (m == 3) ? UIAI2 : UIAI3;
    const int* it_ = (m == 1) ? IUIU : (m == 2) ? IAIU1
                   : (m == 3) ? IAIU2 : IAIU3;
    metapath_body<4>(smem, emb_user, emb_item, u2, emb_item,
                     emb_item, u2, emb_item, emb_user,
                     iu_, it_,
                     BmT + (size_t)m * 49152, WcT + (size_t)m * 49152,
                     Zall, m, tile);
  }
}

// ---------------- fused tail: tanh-GEMM + w + beta + pout + final MLP ------
// block = 1 batch element b, 512 threads (8 waves); grid = 512
__global__ __launch_bounds__(512) void fused_tail(
    const bf16* __restrict__ Zall,    // [512*160][128], row b*160+j
    const bf16* __restrict__ pw1T,    // [128][128] (o-major)
    const float* __restrict__ pb1, const float* __restrict__ pw2,
    const int* __restrict__ UI, const int* __restrict__ IU,
    const float* __restrict__ emb_user, const float* __restrict__ emb_item,
    const float* __restrict__ fw1, const float* __restrict__ fb1,
    const float* __restrict__ fw2, const float* __restrict__ fb2,
    float* __restrict__ out)
{
  __shared__ bf16 Zs[160 * 136];
  __shared__ float wrow[160];
  __shared__ float ph[4][128];
  __shared__ float xs[384];
  __shared__ float sred[16];
  __shared__ float yred[2];

  int b = blockIdx.x, tid = threadIdx.x;
  int lane = tid & 63, wid = tid >> 6;
  int l15 = lane & 15, l4 = lane >> 4;

  // ---- stage z-block (160x128 bf16) -> LDS, raw 16B copies, hoisted ----
  {
    const float4* src = (const float4*)(Zall + (size_t)b * 160 * 128);
    float4 v[5];
    #pragma unroll
    for (int i = 0; i < 5; ++i) v[i] = src[i * 512 + tid];
    #pragma unroll
    for (int i = 0; i < 5; ++i) {
      int idx = i * 512 + tid;            // 0..2559
      int row = idx >> 4, c8 = idx & 15;
      *(float4*)&Zs[row * 136 + c8 * 8] = v[i];
    }
  }
  __syncthreads();

  // ---- w[row] = (tanh(z@pw1+pb1).pw2)*5 : M=160,N=128,K=128 ----
  for (int rf = wid; rf < 10; rf += 8) {
    bfrag a[4];
    #pragma unroll
    for (int kk = 0; kk < 4; ++kk)
      a[kk] = *(const bfrag*)&Zs[(rf * 16 + l15) * 136 + kk * 32 + 8 * l4];
    float part[4] = {0.f, 0.f, 0.f, 0.f};
    #pragma unroll
    for (int f = 0; f < 8; ++f) {
      int col = f * 16 + l15;
      ffrag acc = {0.f, 0.f, 0.f, 0.f};
      #pragma unroll
      for (int kk = 0; kk < 4; ++kk) {
        bfrag bv = *(const bfrag*)&pw1T[(size_t)col * 128 + kk * 32 + 8 * l4];
        acc = __builtin_amdgcn_mfma_f32_16x16x32_bf16(a[kk], bv, acc, 0, 0, 0);
      }
      float bias = pb1[col], w2 = pw2[col];
      #pragma unroll
      for (int r = 0; r < 4; ++r) part[r] += tanhf(acc[r] + bias) * w2;
    }
    #pragma unroll
    for (int d = 1; d < 16; d <<= 1) {
      #pragma unroll
      for (int r = 0; r < 4; ++r) part[r] += __shfl_xor(part[r], d);
    }
    if (l15 == 0) {
      #pragma unroll
      for (int r = 0; r < 4; ++r)
        wrow[rf * 16 + 4 * l4 + r] = part[r] * 5.0f;   // /T2
    }
  }
  __syncthreads();

  // ---- softmax over 160 paths (wave-parallel) ----
  {
    float v = (tid < 160) ? wrow[tid] : -1e30f;
    #pragma unroll
    for (int off = 32; off; off >>= 1) v = fmaxf(v, __shfl_xor(v, off));
    if (lane == 0) sred[wid] = v;
    __syncthreads();
    if (tid < 64) {
      float mval = (lane < 8) ? sred[lane] : -1e30f;
      #pragma unroll
      for (int off = 4; off; off >>= 1) mval = fmaxf(mval, __shfl_xor(mval, off));
      if (lane == 0) sred[8] = mval;
    }
    __syncthreads();
    float mx = sred[8];
    float ev = (tid < 160) ? __expf(wrow[tid] - mx) : 0.f;
    float s = ev;
    #pragma unroll
    for (int off = 32; off; off >>= 1) s += __shfl_xor(s, off);
    if (lane == 0) sred[wid] = s;
    __syncthreads();
    if (tid < 64) {
      float sval = (lane < 8) ? sred[lane] : 0.f;
      #pragma unroll
      for (int off = 4; off; off >>= 1) sval += __shfl_xor(sval, off);
      if (lane == 0) sred[9] = sval;
    }
    __syncthreads();
    if (tid < 160) wrow[tid] = ev / sred[9];
  }
  __syncthreads();

  // ---- pout[e] = sum_j beta[j]*z[j][e]  (4-way split over j) ----
  {
    int e = tid & 127, q = tid >> 7;
    float acc = 0.f;
    #pragma unroll 4
    for (int j = q * 40; j < q * 40 + 40; ++j)
      acc += wrow[j] * __bfloat162float(Zs[j * 136 + e]);
    ph[q][e] = acc;
  }
  __syncthreads();

  // ---- build x = [src_emb, tgt_emb, pout] ----
  {
    int su = UI[b * 64];   // UI[b][0][0]
    int ti = IU[b * 64];   // IU[b][0][0]
    if (tid < 128) {
      xs[256 + tid] = ph[0][tid] + ph[1][tid] + ph[2][tid] + ph[3][tid];
    } else if (tid < 256) {
      xs[tid - 128] = emb_user[(size_t)su * 128 + (tid - 128)];
    } else if (tid < 384) {
      xs[tid - 128] = emb_item[(size_t)ti * 128 + (tid - 256)];
    }
  }
  __syncthreads();

  // ---- final: y = relu(x@fw1+fb1); out = sigmoid(y.fw2+fb2) ----
  {
    int o = tid & 127, q = tid >> 7;
    float acc = 0.f;
    #pragma unroll 4
    for (int i = q * 96; i < q * 96 + 96; ++i)
      acc += xs[i] * fw1[(size_t)i * 128 + o];
    __syncthreads();          // ph free now
    ph[q][o] = acc;
  }
  __syncthreads();
  if (tid < 128) {
    float y = fmaxf(ph[0][tid] + ph[1][tid] + ph[2][tid] + ph[3][tid] + fb1[tid],
                    0.0f) * fw2[tid];
    #pragma unroll
    for (int off = 32; off; off >>= 1) y += __shfl_down(y, off);
    if ((tid & 63) == 0) yred[tid >> 6] = y;
  }
  __syncthreads();
  if (tid == 0) {
    float s = yred[0] + yred[1] + fb2[0];
    out[b] = 1.0f / (1.0f + expf(-s));
  }
}

// ---------------------------------------------------------------------------
extern "C" void kernel_launch(void* const* d_in, const int* in_sizes, int n_in,
                              void* d_out, int out_size, void* d_ws, size_t ws_size,
                              hipStream_t stream)
{
  const int* UI    = (const int*)d_in[0];
  const int* IU    = (const int*)d_in[1];
  const int* UIUI  = (const int*)d_in[2];
  const int* IUIU  = (const int*)d_in[3];
  const int* UIAI1 = (const int*)d_in[4];
  const int* IAIU1 = (const int*)d_in[5];
  const int* UIAI2 = (const int*)d_in[6];
  const int* IAIU2 = (const int*)d_in[7];
  const int* UIAI3 = (const int*)d_in[8];
  const int* IAIU3 = (const int*)d_in[9];
  const float* emb_user = (const float*)d_in[10];
  const float* emb_item = (const float*)d_in[11];
  const float* emb_a1   = (const float*)d_in[12];
  const float* emb_a2   = (const float*)d_in[13];
  const float* emb_a3   = (const float*)d_in[14];
  const float* Wt  = (const float*)d_in[15];
  const float* Ws  = (const float*)d_in[16];
  const float* Wc  = (const float*)d_in[17];
  const float* pw1 = (const float*)d_in[18];
  const float* pb1 = (const float*)d_in[19];
  const float* pw2 = (const float*)d_in[20];
  const float* fw1 = (const float*)d_in[21];
  const float* fb1 = (const float*)d_in[22];
  const float* fw2 = (const float*)d_in[23];
  const float* fb2 = (const float*)d_in[24];
  float* out = (float*)d_out;

  // ---- workspace carve (bytes) ----
  char* wsb = (char*)d_ws;
  bf16*  BmT  = (bf16*)wsb;                         // 491,520 B
  bf16*  WcT  = (bf16*)(wsb + 491520);              // 491,520 B
  bf16*  pw1T = (bf16*)(wsb + 983040);              //  32,768 B
  bf16*  Zall = (bf16*)(wsb + 1015808);             // 20,971,520 B

  prep_all<<<1264, 256, 0, stream>>>(Ws, Wt, Wc, pw1, BmT, WcT, pw1T);

  // dyn LDS (PP=7): Hs 16*952*2 + Ss 16*392*2 + Al 16*24*2
  //              = 30464 + 12544 + 768 = 43776 B
  fused_all<<<5120, 512, 43776, stream>>>(
      emb_user, emb_item, emb_a1, emb_a2, emb_a3,
      UI, IU, UIUI, IUIU, UIAI1, IAIU1, UIAI2, IAIU2, UIAI3, IAIU3,
      BmT, WcT, Zall);

  fused_tail<<<512, 512, 0, stream>>>(Zall, pw1T, pb1, pw2,
                                      UI, IU, emb_user, emb_item,
                                      fw1, fb1, fw2, fb2, out);
}